// Round 1
// baseline (461.913 us; speedup 1.0000x reference)
//
#include <hip/hip_runtime.h>
#include <cstdint>

typedef unsigned short u16;
typedef short bh8 __attribute__((ext_vector_type(8)));
typedef float f32x4 __attribute__((ext_vector_type(4)));

#define EPSF 1.1920929e-07f
#define INV_SQRT2 0.70710678118654752440f

// ---------------- workspace layout (bytes) ----------------
// x_bf16 region is reused as butterflyA's bf16 output (x dead after gemm1)
static constexpr size_t OFF_XB   = 0;                        // 8192*2048*2 = 33554432 (x bf16; later thetaA bf16)
static constexpr size_t OFF_WCAT = 33554432;                 // [2304][2048] bf16 = 9437184
static constexpr size_t OFF_WOUT = OFF_WCAT + 9437184;       // 2048*2048*2 = 8388608
static constexpr size_t OFF_THBF = OFF_WOUT + 8388608;       // 8192*2048*2 = 33554432 (butterflyB out)
static constexpr size_t OFF_PHI  = OFF_THBF + 33554432;      // 8192*192*4 = 6291456
static constexpr size_t OFF_TRA  = OFF_PHI + 6291456;        // cosA(786432 f32) + sinA
static constexpr size_t OFF_TRB  = OFF_TRA + 6291456;        // cosB + sinB
// total = OFF_TRB + 6291456 = 103809024 (~99 MB)

// ---------------- helpers ----------------
__device__ __forceinline__ uint32_t f2bf_rne(float f) {
  uint32_t u = __float_as_uint(f);
  u += 0x7fffu + ((u >> 16) & 1u);
  return u >> 16;
}

__device__ __forceinline__ void gload_lds16(const void* g, void* l) {
  __builtin_amdgcn_global_load_lds(
      (const __attribute__((address_space(1))) void*)g,
      (__attribute__((address_space(3))) void*)l, 16, 0, 0);
}

// ---------------- cast f32 -> bf16 (vectorized, grid-stride) ----------------
__global__ __launch_bounds__(256)
void cast_f32_bf16(const float* __restrict__ src, u16* __restrict__ dst, int n4) {
  int i = blockIdx.x * blockDim.x + threadIdx.x;
  int stride = gridDim.x * blockDim.x;
  for (; i < n4; i += stride) {
    float4 v = ((const float4*)src)[i];
    uint32_t a = __float_as_uint(v.x); a += 0x7fffu + ((a >> 16) & 1u);
    uint32_t b = __float_as_uint(v.y); b += 0x7fffu + ((b >> 16) & 1u);
    uint32_t c = __float_as_uint(v.z); c += 0x7fffu + ((c >> 16) & 1u);
    uint32_t d = __float_as_uint(v.w); d += 0x7fffu + ((d >> 16) & 1u);
    uint2 o;
    o.x = (a >> 16) | (b & 0xffff0000u);
    o.y = (c >> 16) | (d & 0xffff0000u);
    ((uint2*)dst)[i] = o;
  }
}

__global__ __launch_bounds__(256)
void zero_u16(u16* __restrict__ dst, int n) {
  int i = blockIdx.x * blockDim.x + threadIdx.x;
  int stride = gridDim.x * blockDim.x;
  for (; i < n; i += stride) dst[i] = 0;
}

// ---------------- bf16 GEMM: C[m,n] = sum_k A[m,k]*B[n,k]  (NT) ----------------
// 128x128 tile, BK=64, 4 waves (2x2), 16x16x32 bf16 MFMA, global_load_lds w=16,
// T2 XOR swizzle both-sides (pre-swizzled global source + swizzled ds_read).
template<int SPLIT>
__global__ __launch_bounds__(256)
void gemm_bt(const u16* __restrict__ A, const u16* __restrict__ B,
             float* __restrict__ C0, float* __restrict__ C1,
             int K, int ntiles) {
  __shared__ u16 As[128 * 64];
  __shared__ u16 Bs[128 * 64];
  const int tid  = threadIdx.x;
  const int w    = tid >> 6;
  const int lane = tid & 63;
  const int mt = blockIdx.x / ntiles, nt = blockIdx.x % ntiles;
  const int wm = (w >> 1) << 6, wn = (w & 1) << 6;
  const int Kb = K * 2;

  const char* Ab = (const char*)(A + (size_t)mt * 128 * K);
  const char* Bb = (const char*)(B + (size_t)nt * 128 * K);
  char* AsB = (char*)As;
  char* BsB = (char*)Bs;

  const int srow  = w * 8 + (lane >> 3);   // staging row within 32-row group
  const int scolb = (lane & 7) << 4;       // byte col within 128B row

  f32x4 acc[4][4] = {};

  for (int kt = 0; kt < K; kt += 64) {
    #pragma unroll
    for (int i = 0; i < 4; ++i) {
      int row = i * 32 + srow;
      int src = scolb ^ ((row & 7) << 4);  // inverse-swizzled source (G21)
      gload_lds16(Ab + (size_t)row * Kb + kt * 2 + src, AsB + i * 4096 + w * 1024);
      gload_lds16(Bb + (size_t)row * Kb + kt * 2 + src, BsB + i * 4096 + w * 1024);
    }
    __syncthreads();
    #pragma unroll
    for (int kk = 0; kk < 2; ++kk) {
      const int kbyte = kk * 64 + ((lane >> 4) << 4);
      bh8 af[4], bfr[4];
      #pragma unroll
      for (int m = 0; m < 4; ++m) {
        int ar = wm + m * 16 + (lane & 15);
        af[m] = *(const bh8*)(AsB + ar * 128 + (kbyte ^ ((ar & 7) << 4)));
        int br = wn + m * 16 + (lane & 15);
        bfr[m] = *(const bh8*)(BsB + br * 128 + (kbyte ^ ((br & 7) << 4)));
      }
      #pragma unroll
      for (int m = 0; m < 4; ++m)
        #pragma unroll
        for (int n = 0; n < 4; ++n)
          acc[m][n] = __builtin_amdgcn_mfma_f32_16x16x32_bf16(af[m], bfr[n], acc[m][n], 0, 0, 0);
    }
    __syncthreads();
  }

  // C/D layout (m89-verified): col = lane&15, row = (lane>>4)*4 + reg
  const int crow0 = mt * 128 + wm + ((lane >> 4) << 2);
  const int ccol0 = nt * 128 + wn + (lane & 15);
  #pragma unroll
  for (int m = 0; m < 4; ++m) {
    #pragma unroll
    for (int n = 0; n < 4; ++n) {
      int gn = ccol0 + n * 16;
      #pragma unroll
      for (int r = 0; r < 4; ++r) {
        int gm = crow0 + m * 16 + r;
        if (SPLIT) {
          if (gn < 2048)      C0[(size_t)gm * 2048 + gn] = acc[m][n][r];
          else if (gn < 2240) C1[(size_t)gm * 192 + (gn - 2048)] = acc[m][n][r];
        } else {
          C0[(size_t)gm * 2048 + gn] = acc[m][n][r];
        }
      }
    }
  }
}

// ---------------- in-place row RMSNorm over 2048 f32 ----------------
__global__ __launch_bounds__(256)
void rmsnorm_rows(float* __restrict__ th) {
  const int row = blockIdx.x;
  const int tid = threadIdx.x;
  float* p = th + (size_t)row * 2048;
  float4 a = ((const float4*)p)[tid];
  float4 b = ((const float4*)p)[tid + 256];
  float ss = a.x*a.x + a.y*a.y + a.z*a.z + a.w*a.w
           + b.x*b.x + b.y*b.y + b.z*b.z + b.w*b.w;
  #pragma unroll
  for (int o = 32; o > 0; o >>= 1) ss += __shfl_down(ss, o);
  __shared__ float red[4];
  if ((tid & 63) == 0) red[tid >> 6] = ss;
  __syncthreads();
  float tot = red[0] + red[1] + red[2] + red[3];
  float s = rsqrtf(tot * (1.0f / 2048.0f) + EPSF);
  a.x *= s; a.y *= s; a.z *= s; a.w *= s;
  b.x *= s; b.y *= s; b.z *= s; b.w *= s;
  ((float4*)p)[tid] = a;
  ((float4*)p)[tid + 256] = b;
}

// ---------------- phi: RMSNorm(192) + cos/sin tables in 2 layouts ----------------
// trigA: cos[((b*16+h)*6+l)*4096 + t], sin at +786432 floats   (levels 0..5)
// trigB: cos[((b*16+h)*6+(l-6))*4096 + r*64 + q], t = q*64+r    (levels 6..11)
__global__ __launch_bounds__(64)
void phi_pass(const float* __restrict__ phiraw,
              float* __restrict__ trigA, float* __restrict__ trigB) {
  const int row = blockIdx.x;  // b*4096 + t
  const int tid = threadIdx.x;
  const float* pr = phiraw + (size_t)row * 192;
  float v0 = pr[tid], v1 = pr[tid + 64], v2 = pr[tid + 128];
  float ss = v0 * v0 + v1 * v1 + v2 * v2;
  #pragma unroll
  for (int o = 32; o > 0; o >>= 1) ss += __shfl_down(ss, o);
  ss = __shfl(ss, 0);
  const float sc = rsqrtf(ss * (1.0f / 192.0f) + EPSF);
  const int b = row >> 12, t = row & 4095;
  const int q = t >> 6, r = t & 63;
  float v[3] = {v0, v1, v2};
  #pragma unroll
  for (int j = 0; j < 3; ++j) {
    int e = j * 64 + tid;
    int l = e >> 4, h = e & 15;
    float ph = v[j] * sc;
    float sn, cs;
    sincosf(ph, &sn, &cs);
    if (l < 6) {
      size_t idx = ((size_t)((b * 16 + h) * 6 + l)) * 4096 + t;
      trigA[idx] = cs; trigA[idx + 786432] = sn;
    } else {
      size_t idx = ((size_t)((b * 16 + h) * 6 + (l - 6))) * 4096 + (size_t)(r * 64 + q);
      trigB[idx] = cs; trigB[idx + 786432] = sn;
    }
  }
}

// ---------------- butterfly levels 0..5: t-chunks with 63-row halo ----------------
// in: theta f32 [B,T,2048]; out: bf16 [B,T,2048]
__global__ __launch_bounds__(512)
void butterflyA(const float* __restrict__ in, u16* __restrict__ outb,
                const float* __restrict__ trigA) {
  __shared__ float L[512 * 32];
  const int tc = blockIdx.x, ec = blockIdx.y, b = blockIdx.z;
  const int tid = threadIdx.x;
  const int t0 = tc * 449;
  const int e0 = ec * 32;
  const int h = e0 >> 7;
  const int pr = tid >> 3;
  const int c4 = (tid & 7) << 2;

  #pragma unroll
  for (int s = 0; s < 8; ++s) {
    int p = pr + s * 64;
    int t = t0 - 63 + p;
    float4 v = make_float4(0.f, 0.f, 0.f, 0.f);
    if (t >= 0 && t < 4096)
      v = *(const float4*)&in[((size_t)(b * 4096 + t)) * 2048 + e0 + c4];
    *(float4*)&L[p * 32 + c4] = v;
  }
  __syncthreads();

  for (int l = 0; l < 6; ++l) {
    const int step = 1 << l;
    const float* cosT = trigA + ((size_t)((b * 16 + h) * 6 + l)) * 4096;
    const float* sinT = cosT + 786432;
    float4 nv[8];
    #pragma unroll
    for (int s = 0; s < 8; ++s) {
      int p = pr + s * 64;
      int t = t0 - 63 + p;
      float4 cur = *(const float4*)&L[p * 32 + c4];
      float4 prev = make_float4(0.f, 0.f, 0.f, 0.f);
      if (p >= step) prev = *(const float4*)&L[(p - step) * 32 + c4];
      float cs = 0.f, sn = 0.f;
      if (t >= 0 && t < 4096) { cs = cosT[t]; sn = sinT[t]; }  // t<0 slots stay 0
      nv[s].x = (cs * cur.x + sn * prev.x) * INV_SQRT2;
      nv[s].y = (cs * cur.y + sn * prev.y) * INV_SQRT2;
      nv[s].z = (cs * cur.z + sn * prev.z) * INV_SQRT2;
      nv[s].w = (cs * cur.w + sn * prev.w) * INV_SQRT2;
    }
    __syncthreads();
    #pragma unroll
    for (int s = 0; s < 8; ++s) {
      int p = pr + s * 64;
      *(float4*)&L[p * 32 + c4] = nv[s];
    }
    __syncthreads();
  }

  #pragma unroll
  for (int s = 0; s < 8; ++s) {
    int p = pr + s * 64;
    int t = t0 - 63 + p;
    if (p >= 63 && t < 4096) {
      float4 v = *(const float4*)&L[p * 32 + c4];
      uint32_t a = f2bf_rne(v.x), bb = f2bf_rne(v.y), c = f2bf_rne(v.z), d = f2bf_rne(v.w);
      uint2 o;
      o.x = a | (bb << 16);
      o.y = c | (d << 16);
      *(uint2*)&outb[((size_t)(b * 4096 + t)) * 2048 + e0 + c4] = o;
    }
  }
}

// ---------------- butterfly levels 6..11: fixed (r,h), q=0..63, no halo ----------------
// in: bf16 [B,T,2048]; out: bf16 [B,T,2048]
__global__ __launch_bounds__(256)
void butterflyB(const u16* __restrict__ in, u16* __restrict__ outb,
                const float* __restrict__ trigB) {
  __shared__ float L[64 * 128];
  const int r = blockIdx.x, h = blockIdx.y, b = blockIdx.z;
  const int tid = threadIdx.x;
  const int qr = tid >> 5;
  const int d4 = (tid & 31) << 2;

  #pragma unroll
  for (int s = 0; s < 8; ++s) {
    int q = qr + s * 8;
    int t = q * 64 + r;
    uint2 o = *(const uint2*)&in[((size_t)(b * 4096 + t)) * 2048 + h * 128 + d4];
    float4 v;
    v.x = __uint_as_float((o.x & 0xffffu) << 16);
    v.y = __uint_as_float(o.x & 0xffff0000u);
    v.z = __uint_as_float((o.y & 0xffffu) << 16);
    v.w = __uint_as_float(o.y & 0xffff0000u);
    *(float4*)&L[q * 128 + d4] = v;
  }
  __syncthreads();

  for (int l = 0; l < 6; ++l) {
    const int qs = 1 << l;
    const float* cosT = trigB + ((size_t)((b * 16 + h) * 6 + l)) * 4096 + r * 64;
    const float* sinT = cosT + 786432;
    float4 nv[8];
    #pragma unroll
    for (int s = 0; s < 8; ++s) {
      int q = qr + s * 8;
      float4 cur = *(const float4*)&L[q * 128 + d4];
      float4 prev = make_float4(0.f, 0.f, 0.f, 0.f);
      if (q >= qs) prev = *(const float4*)&L[(q - qs) * 128 + d4];
      float cs = cosT[q], sn = sinT[q];
      nv[s].x = (cs * cur.x + sn * prev.x) * INV_SQRT2;
      nv[s].y = (cs * cur.y + sn * prev.y) * INV_SQRT2;
      nv[s].z = (cs * cur.z + sn * prev.z) * INV_SQRT2;
      nv[s].w = (cs * cur.w + sn * prev.w) * INV_SQRT2;
    }
    __syncthreads();
    #pragma unroll
    for (int s = 0; s < 8; ++s) {
      int q = qr + s * 8;
      *(float4*)&L[q * 128 + d4] = nv[s];
    }
    __syncthreads();
  }

  #pragma unroll
  for (int s = 0; s < 8; ++s) {
    int q = qr + s * 8;
    int t = q * 64 + r;
    float4 v = *(const float4*)&L[q * 128 + d4];
    uint32_t a = f2bf_rne(v.x), bb = f2bf_rne(v.y), c = f2bf_rne(v.z), d = f2bf_rne(v.w);
    uint2 o;
    o.x = a | (bb << 16);
    o.y = c | (d << 16);
    *(uint2*)&outb[((size_t)(b * 4096 + t)) * 2048 + h * 128 + d4] = o;
  }
}

// ---------------- launch ----------------
extern "C" void kernel_launch(void* const* d_in, const int* in_sizes, int n_in,
                              void* d_out, int out_size, void* d_ws, size_t ws_size,
                              hipStream_t stream) {
  const float* x    = (const float*)d_in[0];
  const float* Wtok = (const float*)d_in[1];
  const float* Wlvl = (const float*)d_in[2];
  const float* Wout = (const float*)d_in[3];

  char* ws = (char*)d_ws;
  u16*   xb     = (u16*)(ws + OFF_XB);
  u16*   wcat   = (u16*)(ws + OFF_WCAT);
  u16*   woutb  = (u16*)(ws + OFF_WOUT);
  u16*   thbfA  = (u16*)(ws + OFF_XB);     // alias: x_bf16 dead after gemm1
  u16*   thbfB  = (u16*)(ws + OFF_THBF);
  float* phiraw = (float*)(ws + OFF_PHI);
  float* trigA  = (float*)(ws + OFF_TRA);
  float* trigB  = (float*)(ws + OFF_TRB);
  float* out    = (float*)d_out;

  // 1. casts (f32 -> bf16)
  cast_f32_bf16<<<2048, 256, 0, stream>>>(x, xb, 4194304);                    // x
  cast_f32_bf16<<<1024, 256, 0, stream>>>(Wtok, wcat, 1048576);               // W_tok -> rows 0..2047
  cast_f32_bf16<<<384, 256, 0, stream>>>(Wlvl, wcat + (size_t)2048 * 2048, 98304); // W_lvl -> rows 2048..2239
  zero_u16<<<128, 256, 0, stream>>>(wcat + (size_t)2240 * 2048, 131072);      // pad rows 2240..2303
  cast_f32_bf16<<<1024, 256, 0, stream>>>(Wout, woutb, 1048576);              // W_out

  // 2. GEMM1: [8192,2048] x [2304,2048]^T -> theta_raw (d_out, f32) + phi_raw
  gemm_bt<1><<<64 * 18, 256, 0, stream>>>(xb, wcat, out, phiraw, 2048, 18);

  // 3. RMSNorm theta rows in-place (d_out)
  rmsnorm_rows<<<8192, 256, 0, stream>>>(out);

  // 4. phi: RMSNorm + trig tables
  phi_pass<<<8192, 64, 0, stream>>>(phiraw, trigA, trigB);

  // 5. butterfly levels 0..5 (f32 in, bf16 out into x_bf16 region)
  butterflyA<<<dim3(10, 64, 2), 512, 0, stream>>>(out, thbfA, trigA);

  // 6. butterfly levels 6..11 (bf16 -> bf16)
  butterflyB<<<dim3(64, 16, 2), 256, 0, stream>>>(thbfA, thbfB, trigB);

  // 7. GEMM3: theta_bf16 x W_out^T -> d_out (f32)
  gemm_bt<0><<<64 * 16, 256, 0, stream>>>(thbfB, woutb, out, nullptr, 2048, 16);
}